// Round 12
// baseline (890.282 us; speedup 1.0000x reference)
//
#include <hip/hip_runtime.h>
#include <hip/hip_bf16.h>

#define SCALE 0.17677669529663689f  // 32^-0.5

// ---------------- workspace offsets (in floats), total ~210 MB ----------------
#define OFF_S    0UL          // 33,554,432 (FULL batch: 32 bh x 256 k x 4096 x)
#define OFF_XQT  33554432UL   // 4,194,304
#define OFF_XV   37748736UL   // 4,194,304
#define OFF_XKT  41943040UL   // 4,194,304
#define OFF_KQ   46137344UL   // 262,144
#define OFF_KK   46399488UL   // 262,144
#define OFF_KV   46661632UL   // 262,144
#define OFF_KATT 46923776UL   // 262,144
#define OFF_XATT 47185920UL   // 4,194,304
#define OFF_MT   51380224UL   // maskT 4 MB
#define OFF_MORI 52428800UL   // 8192 ints
#define OFF_FLAG 52436992UL

__device__ __forceinline__ float b2f(unsigned int u) {
    union { unsigned int i; float f; } v; v.i = u << 16; return v.f;
}

// ---------------- dtype detection ----------------
__global__ __launch_bounds__(256) void detect_kernel(
    const unsigned int* __restrict__ mask, const unsigned int* __restrict__ xf,
    int* __restrict__ flags)
{
    __shared__ unsigned int orv;
    __shared__ int cnt;
    int t = threadIdx.x;
    if (t == 0) { orv = 0u; cnt = 0; }
    __syncthreads();
    if (blockIdx.x == 0) {
        unsigned int v = 0;
        for (int i = t; i < 16384; i += 256) v |= mask[i];
        atomicOr(&orv, v);
        __syncthreads();
        if (t == 0) {
            unsigned int o = orv;
            int f;
            if (o <= 1u || o == 0x3F800000u) f = 0;
            else if (o & 0x00800080u)        f = 2;
            else                             f = 1;
            flags[0] = f;
        }
    } else {
        int c = 0;
        for (int i = t; i < 4096; i += 256) {
            unsigned int h = xf[i] & 0xFFFFu;
            unsigned int e = (h >> 7) & 0xFFu;
            if (h == 0u || (e >= 0x75u && e <= 0x82u)) c++;
        }
        atomicAdd(&cnt, c);
        __syncthreads();
        if (t == 0) flags[1] = (cnt > 3000) ? 1 : 0;
    }
}

// ---------------- qkv128: mode-0 GEMM, 128x64 tile, 8x4 microtile (split rows) ----
__global__ __launch_bounds__(256) void qkv128_kernel(
    const void* __restrict__ A, const void* __restrict__ W,
    float* __restrict__ oq, float* __restrict__ ok, float* __restrict__ ov,
    const int* __restrict__ flags)
{
    __shared__ __align__(16) float As[16][132];
    __shared__ __align__(16) float Bs[16][64];
    int bf = flags[1];
    const float* A32 = (const float*)A;
    const float* W32 = (const float*)W;
    const unsigned short* A16 = (const unsigned short*)A;
    const unsigned short* W16 = (const unsigned short*)W;
    int m0 = blockIdx.x * 128;
    int n0 = blockIdx.y * 64;
    int id = threadIdx.x;
    int tm = id >> 4, tn = id & 15;
    float acc[8][4] = {};
    for (int k0 = 0; k0 < 256; k0 += 16) {
        int r = id >> 1, ck = (id & 1) * 8;
        int rk = id >> 4, cn = (id & 15) * 4;
        if (bf) {
            uint4 a4 = *(const uint4*)&A16[(size_t)(m0 + r) * 256 + k0 + ck];
            As[ck + 0][r] = b2f(a4.x & 0xFFFFu); As[ck + 1][r] = b2f(a4.x >> 16);
            As[ck + 2][r] = b2f(a4.y & 0xFFFFu); As[ck + 3][r] = b2f(a4.y >> 16);
            As[ck + 4][r] = b2f(a4.z & 0xFFFFu); As[ck + 5][r] = b2f(a4.z >> 16);
            As[ck + 6][r] = b2f(a4.w & 0xFFFFu); As[ck + 7][r] = b2f(a4.w >> 16);
            uint2 w2 = *(const uint2*)&W16[(size_t)(k0 + rk) * 768 + n0 + cn];
            Bs[rk][cn + 0] = b2f(w2.x & 0xFFFFu); Bs[rk][cn + 1] = b2f(w2.x >> 16);
            Bs[rk][cn + 2] = b2f(w2.y & 0xFFFFu); Bs[rk][cn + 3] = b2f(w2.y >> 16);
        } else {
            float4 a0 = *(const float4*)&A32[(size_t)(m0 + r) * 256 + k0 + ck];
            float4 a1 = *(const float4*)&A32[(size_t)(m0 + r) * 256 + k0 + ck + 4];
            As[ck + 0][r] = a0.x; As[ck + 1][r] = a0.y;
            As[ck + 2][r] = a0.z; As[ck + 3][r] = a0.w;
            As[ck + 4][r] = a1.x; As[ck + 5][r] = a1.y;
            As[ck + 6][r] = a1.z; As[ck + 7][r] = a1.w;
            *(float4*)&Bs[rk][cn] = *(const float4*)&W32[(size_t)(k0 + rk) * 768 + n0 + cn];
        }
        __syncthreads();
        #pragma unroll
        for (int kk = 0; kk < 16; kk++) {
            float a[8], b[4];
            *(float4*)&a[0] = *(const float4*)&As[kk][tm * 4];
            *(float4*)&a[4] = *(const float4*)&As[kk][64 + tm * 4];
            *(float4*)&b[0] = *(const float4*)&Bs[kk][tn * 4];
            #pragma unroll
            for (int i = 0; i < 8; i++)
                #pragma unroll
                for (int j = 0; j < 4; j++)
                    acc[i][j] = fmaf(a[i], b[j], acc[i][j]);
        }
        __syncthreads();
    }
    int sec = n0 >> 8;
    int b = m0 >> 12;
    if (sec < 2) {
        int rr0 = (m0 & 4095) + tm * 4;
        float* dstb = (sec == 0) ? oq : ok;
        #pragma unroll
        for (int j = 0; j < 4; j++) {
            int col = n0 + tn * 4 + j;
            int hh = (col >> 5) & 7, d = col & 31;
            size_t base = (((size_t)(b * 8 + hh)) * 32 + d) * 4096 + rr0;
            *(float4*)&dstb[base]      = make_float4(acc[0][j], acc[1][j], acc[2][j], acc[3][j]);
            *(float4*)&dstb[base + 64] = make_float4(acc[4][j], acc[5][j], acc[6][j], acc[7][j]);
        }
    } else {
        int col0 = n0 + tn * 4;
        int hh = (col0 >> 5) & 7, d0 = col0 & 31;
        #pragma unroll
        for (int i = 0; i < 8; i++) {
            int rr = (m0 & 4095) + (i < 4 ? tm * 4 + i : 64 + tm * 4 + (i - 4));
            *(float4*)&ov[(((size_t)(b * 8 + hh)) * 4096 + rr) * 32 + d0] =
                make_float4(acc[i][0], acc[i][1], acc[i][2], acc[i][3]);
        }
    }
}

// ---------------- qkv (mode-1, kernal): 64x64 tile ----------------
__global__ __launch_bounds__(256) void qkv_kernel(
    const void* __restrict__ A, const void* __restrict__ W,
    float* __restrict__ oq, float* __restrict__ ok, float* __restrict__ ov,
    const int* __restrict__ flags)
{
    __shared__ __align__(16) float As[16][68];
    __shared__ __align__(16) float Bs[16][64];
    int bf = flags[1];
    const float* A32 = (const float*)A;
    const float* W32 = (const float*)W;
    const unsigned short* A16 = (const unsigned short*)A;
    const unsigned short* W16 = (const unsigned short*)W;
    int m0 = blockIdx.x * 64;
    int n0 = blockIdx.y * 64;
    int id = threadIdx.x;
    int tm = id >> 4, tn = id & 15;
    float acc[4][4] = {};
    for (int k0 = 0; k0 < 256; k0 += 16) {
        int r = id >> 2, ck = (id & 3) * 4;
        int rk = id >> 4, cn = (id & 15) * 4;
        if (bf) {
            uint2 a2 = *(const uint2*)&A16[(size_t)(m0 + r) * 256 + k0 + ck];
            As[ck + 0][r] = b2f(a2.x & 0xFFFFu); As[ck + 1][r] = b2f(a2.x >> 16);
            As[ck + 2][r] = b2f(a2.y & 0xFFFFu); As[ck + 3][r] = b2f(a2.y >> 16);
            uint2 w2 = *(const uint2*)&W16[(size_t)(k0 + rk) * 768 + n0 + cn];
            Bs[rk][cn + 0] = b2f(w2.x & 0xFFFFu); Bs[rk][cn + 1] = b2f(w2.x >> 16);
            Bs[rk][cn + 2] = b2f(w2.y & 0xFFFFu); Bs[rk][cn + 3] = b2f(w2.y >> 16);
        } else {
            float4 a4 = *(const float4*)&A32[(size_t)(m0 + r) * 256 + k0 + ck];
            As[ck + 0][r] = a4.x; As[ck + 1][r] = a4.y;
            As[ck + 2][r] = a4.z; As[ck + 3][r] = a4.w;
            *(float4*)&Bs[rk][cn] = *(const float4*)&W32[(size_t)(k0 + rk) * 768 + n0 + cn];
        }
        __syncthreads();
        #pragma unroll
        for (int kk = 0; kk < 16; kk++) {
            float4 a = *(const float4*)&As[kk][tm * 4];
            float4 b = *(const float4*)&Bs[kk][tn * 4];
            float av[4] = {a.x, a.y, a.z, a.w};
            float bv[4] = {b.x, b.y, b.z, b.w};
            #pragma unroll
            for (int i = 0; i < 4; i++)
                #pragma unroll
                for (int j = 0; j < 4; j++)
                    acc[i][j] = fmaf(av[i], bv[j], acc[i][j]);
        }
        __syncthreads();
    }
    #pragma unroll
    for (int i = 0; i < 4; i++) {
        int row = m0 + tm * 4 + i;
        int b = row >> 8, rr = row & 255;
        #pragma unroll
        for (int j = 0; j < 4; j++) {
            int col = n0 + tn * 4 + j;
            int s2 = col >> 8, hh = (col >> 5) & 7, d = col & 31;
            float* dst = s2 == 0 ? oq : (s2 == 1 ? ok : ov);
            dst[(((size_t)(b * 8 + hh)) * 256 + rr) * 32 + d] = acc[i][j];
        }
    }
}

// ---------------- mask bit-packing ----------------
__global__ __launch_bounds__(256) void maskpack_kernel(
    const void* __restrict__ mask, unsigned int* __restrict__ maskT,
    const int* __restrict__ flags)
{
    int bh = blockIdx.x >> 7;
    int x0 = (blockIdx.x & 127) * 32;
    int t = threadIdx.x;
    int wv = t >> 6, lane = t & 63;
    int mode = flags[0];
    __shared__ unsigned int lds[32][8];
    for (int it = 0; it < 8; it++) {
        int xl = wv * 8 + it;
        size_t rb = ((size_t)bh * 4096 + x0 + xl) * 256;
        unsigned int nib;
        if (mode == 0) {
            uint4 m = ((const uint4*)((const unsigned int*)mask + rb))[lane];
            nib = (unsigned int)(m.x != 0u) | ((unsigned int)(m.y != 0u) << 1)
                | ((unsigned int)(m.z != 0u) << 2) | ((unsigned int)(m.w != 0u) << 3);
        } else if (mode == 1) {
            unsigned int m = ((const unsigned int*)mask)[rb / 4 + lane];
            nib = (unsigned int)((m & 0xFFu) != 0u) | ((unsigned int)((m & 0xFF00u) != 0u) << 1)
                | ((unsigned int)((m & 0xFF0000u) != 0u) << 2)
                | ((unsigned int)((m & 0xFF000000u) != 0u) << 3);
        } else {
            uint2 m = ((const uint2*)((const unsigned short*)mask + rb))[lane];
            nib = (unsigned int)((m.x & 0xFFFFu) != 0u) | ((unsigned int)((m.x >> 16) != 0u) << 1)
                | ((unsigned int)((m.y & 0xFFFFu) != 0u) << 2)
                | ((unsigned int)((m.y >> 16) != 0u) << 3);
        }
        unsigned long long b0 = __ballot((nib & 1u) != 0u);
        unsigned long long b1 = __ballot((nib & 2u) != 0u);
        unsigned long long b2 = __ballot((nib & 4u) != 0u);
        unsigned long long b3 = __ballot((nib & 8u) != 0u);
        if (lane < 8) {
            int j = lane >> 1;
            unsigned long long bb = j == 0 ? b0 : j == 1 ? b1 : j == 2 ? b2 : b3;
            lds[xl][lane] = (lane & 1) ? (unsigned int)(bb >> 32) : (unsigned int)bb;
        }
    }
    __syncthreads();
    int widx = (t & 3) * 2 + (t >> 7);
    int bitpos = (t >> 2) & 31;
    unsigned int w = 0u;
    #pragma unroll
    for (int xl = 0; xl < 32; xl++)
        w |= ((lds[xl][widx] >> bitpos) & 1u) << xl;
    maskT[((size_t)bh * 256 + t) * 128 + (x0 >> 5)] = w;
}

// ---------------- S1 = scale * kq (256x32) @ xkT (32x4096), FULL batch ----------------
__global__ __launch_bounds__(256) void s1_kernel(
    const float* __restrict__ kq, const float* __restrict__ xkT, float* __restrict__ S)
{
    __shared__ __align__(16) float Aq[32][68];
    __shared__ __align__(16) float Bs[32][64];
    size_t bhg = (size_t)blockIdx.z;
    int k0 = blockIdx.y * 64;
    int x0 = blockIdx.x * 64;
    int id = threadIdx.x;
    {
        int c4 = (id & 7) * 4;
        #pragma unroll
        for (int rep = 0; rep < 2; rep++) {
            int r = (id >> 3) + rep * 32;
            float4 a = *(const float4*)&kq[(bhg * 256 + k0 + r) * 32 + c4];
            Aq[c4 + 0][r] = a.x; Aq[c4 + 1][r] = a.y;
            Aq[c4 + 2][r] = a.z; Aq[c4 + 3][r] = a.w;
        }
    }
    {
        int c = (id & 15) * 4;
        #pragma unroll
        for (int rep = 0; rep < 2; rep++) {
            int r = (id >> 4) + rep * 16;
            *(float4*)&Bs[r][c] = *(const float4*)&xkT[(bhg * 32 + r) * 4096 + x0 + c];
        }
    }
    __syncthreads();
    int tm = id >> 4, tn = id & 15;
    float acc[4][4] = {};
    #pragma unroll
    for (int dd = 0; dd < 32; dd++) {
        float4 a = *(const float4*)&Aq[dd][tm * 4];
        float4 b = *(const float4*)&Bs[dd][tn * 4];
        float av[4] = {a.x, a.y, a.z, a.w};
        float bv[4] = {b.x, b.y, b.z, b.w};
        #pragma unroll
        for (int i = 0; i < 4; i++)
            #pragma unroll
            for (int j = 0; j < 4; j++)
                acc[i][j] = fmaf(av[i], bv[j], acc[i][j]);
    }
    #pragma unroll
    for (int i = 0; i < 4; i++) {
        float4 o;
        o.x = acc[i][0] * SCALE; o.y = acc[i][1] * SCALE;
        o.z = acc[i][2] * SCALE; o.w = acc[i][3] * SCALE;
        *(float4*)&S[(bhg * 256 + k0 + tm * 4 + i) * 4096 + x0 + tn * 4] = o;
    }
}

// ---------------- path-1: argmax + bias + FULL softmax written back to S ----------------
__global__ __launch_bounds__(256) void p1_softmax_kernel(
    float* __restrict__ S,
    const int* __restrict__ rd, const int* __restrict__ polar,
    const unsigned int* __restrict__ maskT,
    const void* __restrict__ dis_emb, const void* __restrict__ polar_emb,
    int* __restrict__ mori, const int* __restrict__ flags)
{
    int idx = blockIdx.x;
    int b = idx >> 11;
    int k = (idx >> 3) & 255;
    int h = idx & 7;
    int bh = b * 8 + h;
    int bhk = bh * 256 + k;
    int t = threadIdx.x;
    int bf = flags[1];
    __shared__ float disc[66];
    __shared__ float pem[8];
    __shared__ float osum[8];
    __shared__ float red[8];
    __shared__ int mo_s;
    if (t < 66) disc[t] = bf ? b2f(((const unsigned short*)dis_emb)[t * 8 + h])
                             : ((const float*)dis_emb)[t * 8 + h];
    if (t < 8) {
        pem[t] = bf ? b2f(((const unsigned short*)polar_emb)[t])
                    : ((const float*)polar_emb)[t];
        osum[t] = 0.f;
    }
    __syncthreads();

    float* srow = &S[(size_t)bhk * 4096];
    const int* prow = &polar[((size_t)b * 256 + k) * 4096];
    const int* rrow = &rd[((size_t)b * 256 + k) * 4096];

    float s[16]; int po[16];
    float loc[8] = {0.f, 0.f, 0.f, 0.f, 0.f, 0.f, 0.f, 0.f};
    #pragma unroll
    for (int i = 0; i < 16; i++) {
        int x = t + i * 256;
        s[i] = srow[x];
        int p = prow[x];
        p = p < 0 ? 0 : (p > 7 ? 7 : p);
        po[i] = p;
        float a = fabsf(s[i]);
        #pragma unroll
        for (int o = 0; o < 8; o++) loc[o] += (p == o) ? a : 0.f;
    }
    #pragma unroll
    for (int o = 0; o < 8; o++) {
        float v = loc[o];
        #pragma unroll
        for (int m = 32; m; m >>= 1) v += __shfl_xor(v, m);
        if ((t & 63) == 0) atomicAdd(&osum[o], v);
    }
    __syncthreads();
    if (t == 0) {
        float best = osum[0]; int bi = 0;
        #pragma unroll
        for (int o = 1; o < 8; o++) if (osum[o] > best) { best = osum[o]; bi = o; }
        mo_s = bi;
        mori[bhk] = bi;
    }
    __syncthreads();
    int mo = mo_s;
    const unsigned int* mrow = &maskT[(size_t)bhk * 128];
    float mx = -3.4e38f;
    #pragma unroll
    for (int i = 0; i < 16; i++) {
        int x = t + i * 256;
        float bias = disc[rrow[x]] + pem[(po[i] - mo + 8) & 7];
        unsigned int w = mrow[x >> 5];
        float l = (((w >> (x & 31)) & 1u) ? -1e6f : s[i]) + bias;
        s[i] = l;
        mx = fmaxf(mx, l);
    }
    #pragma unroll
    for (int m = 32; m; m >>= 1) mx = fmaxf(mx, __shfl_xor(mx, m));
    if ((t & 63) == 0) red[t >> 6] = mx;
    __syncthreads();
    mx = fmaxf(fmaxf(red[0], red[1]), fmaxf(red[2], red[3]));
    float sum = 0.f;
    #pragma unroll
    for (int i = 0; i < 16; i++) { s[i] = __expf(s[i] - mx); sum += s[i]; }
    #pragma unroll
    for (int m = 32; m; m >>= 1) sum += __shfl_xor(sum, m);
    if ((t & 63) == 0) red[4 + (t >> 6)] = sum;
    __syncthreads();
    sum = red[4] + red[5] + red[6] + red[7];
    float inv = 1.f / sum;
    #pragma unroll
    for (int i = 0; i < 16; i++) srow[t + i * 256] = s[i] * inv;
}

// ---------------- av1 v3: P rows in registers (global), Vt-only LDS ----------------
// k_att += P (256x4096) @ xv (4096x32). Thread (r,p) handles rows k0+r, k0+64+r,
// d-slice p*8..p*8+7. grid: (32 xs, 2 ktiles, 32 bh)
__global__ __launch_bounds__(256) void av1_kernel(
    const float* __restrict__ S, const float* __restrict__ xv, float* __restrict__ k_att)
{
    __shared__ __align__(16) float Vt[64][32];
    int bhg = blockIdx.z, b = bhg >> 3, h = bhg & 7;
    int k0 = blockIdx.y * 128;
    int xs = blockIdx.x;
    int id = threadIdx.x;
    int r = id >> 2, p = id & 3;
    int kA = k0 + r, kB = k0 + 64 + r;
    const float* rowA = &S[((size_t)bhg * 256 + kA) * 4096];
    const float* rowB = &S[((size_t)bhg * 256 + kB) * 4096];
    float accA[8] = {}, accB[8] = {};
    for (int c8 = 0; c8 < 2; c8++) {
        int xc = xs * 128 + c8 * 64;
        if (c8) __syncthreads();
        {
            int c = (id & 7) * 4;
            #pragma unroll
            for (int rep = 0; rep < 2; rep++) {
                int rr = (id >> 3) + rep * 32;
                *(float4*)&Vt[rr][c] = *(const float4*)&xv[((size_t)bhg * 4096 + xc + rr) * 32 + c];
            }
        }
        __syncthreads();
        #pragma unroll
        for (int s = 0; s < 4; s++) {
            float4 a4[4], b4[4];
            #pragma unroll
            for (int j = 0; j < 4; j++) {
                a4[j] = *(const float4*)&rowA[xc + s * 16 + j * 4];
                b4[j] = *(const float4*)&rowB[xc + s * 16 + j * 4];
            }
            const float* pA = (const float*)a4;
            const float* pB = (const float*)b4;
            #pragma unroll
            for (int u = 0; u < 16; u++) {
                float pa = pA[u], pb = pB[u];
                float4 v0 = *(const float4*)&Vt[s * 16 + u][p * 8];
                float4 v1 = *(const float4*)&Vt[s * 16 + u][p * 8 + 4];
                accA[0] = fmaf(pa, v0.x, accA[0]);
                accA[1] = fmaf(pa, v0.y, accA[1]);
                accA[2] = fmaf(pa, v0.z, accA[2]);
                accA[3] = fmaf(pa, v0.w, accA[3]);
                accA[4] = fmaf(pa, v1.x, accA[4]);
                accA[5] = fmaf(pa, v1.y, accA[5]);
                accA[6] = fmaf(pa, v1.z, accA[6]);
                accA[7] = fmaf(pa, v1.w, accA[7]);
                accB[0] = fmaf(pb, v0.x, accB[0]);
                accB[1] = fmaf(pb, v0.y, accB[1]);
                accB[2] = fmaf(pb, v0.z, accB[2]);
                accB[3] = fmaf(pb, v0.w, accB[3]);
                accB[4] = fmaf(pb, v1.x, accB[4]);
                accB[5] = fmaf(pb, v1.y, accB[5]);
                accB[6] = fmaf(pb, v1.z, accB[6]);
                accB[7] = fmaf(pb, v1.w, accB[7]);
            }
        }
    }
    float* dstA = &k_att[((size_t)b * 256 + kA) * 256 + h * 32 + p * 8];
    float* dstB = &k_att[((size_t)b * 256 + kB) * 256 + h * 32 + p * 8];
    #pragma unroll
    for (int j = 0; j < 8; j++) {
        atomicAdd(&dstA[j], accA[j]);
        atomicAdd(&dstB[j], accB[j]);
    }
}

// ---------------- fa2: kc=32 chunks, transposed P tile, FULL batch ----
__global__ __launch_bounds__(256) void fa2_kernel(
    const float* __restrict__ kk, const float* __restrict__ xqT, const float* __restrict__ kv,
    const int* __restrict__ rd, const int* __restrict__ polar,
    const unsigned int* __restrict__ maskT,
    const void* __restrict__ dis_emb, const void* __restrict__ polar_emb,
    const int* __restrict__ mori, const int* __restrict__ flags,
    float* __restrict__ x_att)
{
    __shared__ __align__(16) float Aq[32][34];
    __shared__ __align__(16) float Bs[32][64];
    __shared__ __align__(16) float At2[64][34];
    __shared__ __align__(16) float Vt[32][32];
    __shared__ float disc[66];
    __shared__ float pem[8];
    __shared__ int mo_l[256];
    int bhg = blockIdx.y, b = bhg >> 3, h = bhg & 7;
    int x0 = blockIdx.x * 64;
    int id = threadIdx.x;
    int bf = flags[1];
    if (id < 66) disc[id] = bf ? b2f(((const unsigned short*)dis_emb)[id * 8 + h])
                               : ((const float*)dis_emb)[id * 8 + h];
    if (id < 8) pem[id] = bf ? b2f(((const unsigned short*)polar_emb)[id])
                             : ((const float*)polar_emb)[id];
    mo_l[id] = mori[(size_t)bhg * 256 + id];
    {
        int c = (id & 15) * 4;
        #pragma unroll
        for (int rep = 0; rep < 2; rep++) {
            int r = (id >> 4) + rep * 16;
            *(float4*)&Bs[r][c] = *(const float4*)&xqT[((size_t)bhg * 32 + r) * 4096 + x0 + c];
        }
    }
    int tm = id >> 4, tn = id & 15;
    int xr = id >> 2, p = id & 3;
    float acc8[8] = {};
    float m = -3.0e38f, l = 0.f;
    for (int kc = 0; kc < 256; kc += 32) {
        __syncthreads();
        {
            int r = id >> 3, c4 = (id & 7) * 4;
            float4 a = *(const float4*)&kk[((size_t)bhg * 256 + kc + r) * 32 + c4];
            Aq[c4 + 0][r] = a.x; Aq[c4 + 1][r] = a.y;
            Aq[c4 + 2][r] = a.z; Aq[c4 + 3][r] = a.w;
            *(float4*)&Vt[r][c4] = *(const float4*)&kv[((size_t)bhg * 256 + kc + r) * 32 + c4];
        }
        __syncthreads();
        float acc[2][4] = {};
        #pragma unroll
        for (int dd = 0; dd < 32; dd++) {
            float2 a2 = *(const float2*)&Aq[dd][tm * 2];
            float4 b4 = *(const float4*)&Bs[dd][tn * 4];
            float bv[4] = {b4.x, b4.y, b4.z, b4.w};
            #pragma unroll
            for (int j = 0; j < 4; j++) {
                acc[0][j] = fmaf(a2.x, bv[j], acc[0][j]);
                acc[1][j] = fmaf(a2.y, bv[j], acc[1][j]);
            }
        }
        int xb = x0 + tn * 4;
        #pragma unroll
        for (int i = 0; i < 2; i++) {
            int kl = tm * 2 + i;
            int k = kc + kl;
            int mo = mo_l[k];
            size_t rib = ((size_t)b * 256 + k) * 4096 + xb;
            int4 r4 = *(const int4*)&rd[rib];
            int4 p4 = *(const int4*)&polar[rib];
            unsigned int mw = maskT[((size_t)bhg * 256 + k) * 128 + (xb >> 5)];
            int rv[4] = {r4.x, r4.y, r4.z, r4.w};
            int pv[4] = {p4.x, p4.y, p4.z, p4.w};
            #pragma unroll
            for (int j = 0; j < 4; j++) {
                int pp = pv[j];
                pp = pp < 0 ? 0 : (pp > 7 ? 7 : pp);
                float bias = disc[rv[j]] + pem[(pp - mo + 8) & 7];
                float s = acc[i][j] * SCALE;
                At2[tn * 4 + j][kl] =
                    (((mw >> ((xb + j) & 31)) & 1u) ? -1e9f : s) + bias;
            }
        }
        __syncthreads();
        float mc = -3.0e38f;
        #pragma unroll
        for (int q4 = 0; q4 < 32; q4 += 4) {
            float4 v = *(const float4*)&At2[xr][q4];
            mc = fmaxf(mc, fmaxf(fmaxf(v.x, v.y), fmaxf(v.z, v.w)));
        }
        float mn = fmaxf(m, mc);
        float f = __expf(m - mn);
        m = mn;
        l *= f;
        #pragma unroll
        for (int j = 0; j < 8; j++) acc8[j] *= f;
        #pragma unroll
        for (int q4 = 0; q4 < 32; q4 += 4) {
            float4 lv = *(const float4*)&At2[xr][q4];
            float le[4] = {lv.x, lv.y, lv.z, lv.w};
            #pragma unroll
            for (int u = 0; u < 4; u++) {
                float e = __expf(le[u] - m);
                l += e;
                float4 v0 = *(const float4*)&Vt[q4 + u][p * 8];
                float4 v1 = *(const float4*)&Vt[q4 + u][p * 8 + 4];
                acc8[0] = fmaf(e, v0.x, acc8[0]);
                acc8[1] = fmaf(e, v0.y, acc8[1]);
                acc8[2] = fmaf(e, v0.z, acc8[2]);
                acc8[3] = fmaf(e, v0.w, acc8[3]);
                acc8[4] = fmaf(e, v1.x, acc8[4]);
                acc8[5] = fmaf(e, v1.y, acc8[5]);
                acc8[6] = fmaf(e, v1.z, acc8[6]);
                acc8[7] = fmaf(e, v1.w, acc8[7]);
            }
        }
    }
    float inv = 1.f / l;
    float* dst = &x_att[((size_t)b * 4096 + x0 + xr) * 256 + h * 32 + p * 8];
    *(float4*)&dst[0] = make_float4(acc8[0] * inv, acc8[1] * inv, acc8[2] * inv, acc8[3] * inv);
    *(float4*)&dst[4] = make_float4(acc8[4] * inv, acc8[5] * inv, acc8[6] * inv, acc8[7] * inv);
}

// ---------------- final projection ----------------
__global__ __launch_bounds__(256) void proj_kernel(
    const float* __restrict__ A, const void* __restrict__ W, const void* __restrict__ bias,
    float* __restrict__ out, const int* __restrict__ flags)
{
    __shared__ __align__(16) float As[16][68];
    __shared__ __align__(16) float Bs[16][64];
    int bf = flags[1];
    const float* W32 = (const float*)W;
    const unsigned short* W16 = (const unsigned short*)W;
    int m0 = blockIdx.x * 64, n0 = blockIdx.y * 64;
    int id = threadIdx.x, tm = id >> 4, tn = id & 15;
    float acc[4][4] = {};
    for (int k0 = 0; k0 < 256; k0 += 16) {
        int rr = id >> 2, ck = (id & 3) * 4;
        int rk = id >> 4, cn = (id & 15) * 4;
        {
            float4 a4 = *(const float4*)&A[(size_t)(m0 + rr) * 256 + k0 + ck];
            As[ck + 0][rr] = a4.x; As[ck + 1][rr] = a4.y;
            As[ck + 2][rr] = a4.z; As[ck + 3][rr] = a4.w;
        }
        if (bf) {
            uint2 w2 = *(const uint2*)&W16[(size_t)(k0 + rk) * 256 + n0 + cn];
            Bs[rk][cn + 0] = b2f(w2.x & 0xFFFFu); Bs[rk][cn + 1] = b2f(w2.x >> 16);
            Bs[rk][cn + 2] = b2f(w2.y & 0xFFFFu); Bs[rk][cn + 3] = b2f(w2.y >> 16);
        } else {
            *(float4*)&Bs[rk][cn] = *(const float4*)&W32[(size_t)(k0 + rk) * 256 + n0 + cn];
        }
        __syncthreads();
        #pragma unroll
        for (int kk = 0; kk < 16; kk++) {
            float4 a = *(const float4*)&As[kk][tm * 4];
            float4 b = *(const float4*)&Bs[kk][tn * 4];
            float av[4] = {a.x, a.y, a.z, a.w};
            float bv[4] = {b.x, b.y, b.z, b.w};
            #pragma unroll
            for (int i = 0; i < 4; i++)
                #pragma unroll
                for (int j = 0; j < 4; j++)
                    acc[i][j] = fmaf(av[i], bv[j], acc[i][j]);
        }
        __syncthreads();
    }
    #pragma unroll
    for (int i = 0; i < 4; i++) {
        int col = n0 + tn * 4;
        float b0 = bf ? b2f(((const unsigned short*)bias)[col + 0]) : ((const float*)bias)[col + 0];
        float b1 = bf ? b2f(((const unsigned short*)bias)[col + 1]) : ((const float*)bias)[col + 1];
        float b2v = bf ? b2f(((const unsigned short*)bias)[col + 2]) : ((const float*)bias)[col + 2];
        float b3 = bf ? b2f(((const unsigned short*)bias)[col + 3]) : ((const float*)bias)[col + 3];
        float4 o = make_float4(acc[i][0] + b0, acc[i][1] + b1, acc[i][2] + b2v, acc[i][3] + b3);
        *(float4*)&out[(size_t)(m0 + tm * 4 + i) * 256 + col] = o;
    }
}

extern "C" void kernel_launch(void* const* d_in, const int* in_sizes, int n_in,
                              void* d_out, int out_size, void* d_ws, size_t ws_size,
                              hipStream_t stream) {
    (void)in_sizes; (void)n_in; (void)out_size; (void)ws_size;
    const void* x         = d_in[0];
    const void* kern      = d_in[1];
    const int*  rd        = (const int*)d_in[2];
    const int*  polar     = (const int*)d_in[3];
    const void* amask     = d_in[4];
    const void* w_qkv     = d_in[5];
    const void* w_proj    = d_in[6];
    const void* b_proj    = d_in[7];
    const void* polar_emb = d_in[8];
    const void* dis_emb   = d_in[9];
    float* out = (float*)d_out;

    float* ws = (float*)d_ws;
    float* S     = ws + OFF_S;
    float* xqT   = ws + OFF_XQT;
    float* xv    = ws + OFF_XV;
    float* xkT   = ws + OFF_XKT;
    float* kq    = ws + OFF_KQ;
    float* kkM   = ws + OFF_KK;
    float* kvM   = ws + OFF_KV;
    float* k_att = ws + OFF_KATT;
    float* x_att = ws + OFF_XATT;
    unsigned int* maskT = (unsigned int*)(ws + OFF_MT);
    int* mori  = (int*)(ws + OFF_MORI);
    int* flags = (int*)(ws + OFF_FLAG);

    detect_kernel<<<2, 256, 0, stream>>>((const unsigned int*)amask, (const unsigned int*)x, flags);
    qkv128_kernel<<<dim3(128, 12), 256, 0, stream>>>(x, w_qkv, xqT, xkT, xv, flags);
    qkv_kernel<<<dim3(16, 12), 256, 0, stream>>>(kern, w_qkv, kq, kkM, kvM, flags);
    maskpack_kernel<<<4096, 256, 0, stream>>>(amask, maskT, flags);
    hipMemsetAsync(k_att, 0, 262144 * sizeof(float), stream);

    // FULL-batch pipeline
    s1_kernel<<<dim3(64, 4, 32), 256, 0, stream>>>(kq, xkT, S);
    p1_softmax_kernel<<<8192, 256, 0, stream>>>(S, rd, polar, maskT, dis_emb, polar_emb,
                                                mori, flags);
    av1_kernel<<<dim3(32, 2, 32), 256, 0, stream>>>(S, xv, k_att);
    fa2_kernel<<<dim3(64, 32), 256, 0, stream>>>(kkM, xqT, kvM, rd, polar, maskT,
                                                 dis_emb, polar_emb, mori, flags, x_att);

    proj_kernel<<<dim3(256, 4), 256, 0, stream>>>(x_att, w_proj, b_proj, out, flags);
    proj_kernel<<<dim3(16, 4), 256, 0, stream>>>(k_att, w_proj, b_proj, out + 4194304, flags);
}

// Round 13
// 731.409 us; speedup vs baseline: 1.2172x; 1.2172x over previous
//
#include <hip/hip_runtime.h>
#include <hip/hip_bf16.h>

#define SCALE 0.17677669529663689f  // 32^-0.5

// ---------------- workspace offsets (in floats), total ~210 MB ----------------
#define OFF_S    0UL          // 33,554,432 (FULL batch: 32 bh x 256 k x 4096 x)
#define OFF_XQT  33554432UL   // 4,194,304
#define OFF_XV   37748736UL   // 4,194,304
#define OFF_XKT  41943040UL   // 4,194,304
#define OFF_KQ   46137344UL   // 262,144
#define OFF_KK   46399488UL   // 262,144
#define OFF_KV   46661632UL   // 262,144
#define OFF_KATT 46923776UL   // 262,144
#define OFF_XATT 47185920UL   // 4,194,304
#define OFF_MT   51380224UL   // maskT 4 MB
#define OFF_MORI 52428800UL   // 8192 ints
#define OFF_FLAG 52436992UL

__device__ __forceinline__ float b2f(unsigned int u) {
    union { unsigned int i; float f; } v; v.i = u << 16; return v.f;
}
__device__ __forceinline__ unsigned short f2b(float f) {
    __hip_bfloat16 h = __float2bfloat16(f);
    return *(unsigned short*)&h;
}

// ---------------- dtype detection ----------------
__global__ __launch_bounds__(256) void detect_kernel(
    const unsigned int* __restrict__ mask, const unsigned int* __restrict__ xf,
    int* __restrict__ flags)
{
    __shared__ unsigned int orv;
    __shared__ int cnt;
    int t = threadIdx.x;
    if (t == 0) { orv = 0u; cnt = 0; }
    __syncthreads();
    if (blockIdx.x == 0) {
        unsigned int v = 0;
        for (int i = t; i < 16384; i += 256) v |= mask[i];
        atomicOr(&orv, v);
        __syncthreads();
        if (t == 0) {
            unsigned int o = orv;
            int f;
            if (o <= 1u || o == 0x3F800000u) f = 0;
            else if (o & 0x00800080u)        f = 2;
            else                             f = 1;
            flags[0] = f;
        }
    } else {
        int c = 0;
        for (int i = t; i < 4096; i += 256) {
            unsigned int h = xf[i] & 0xFFFFu;
            unsigned int e = (h >> 7) & 0xFFu;
            if (h == 0u || (e >= 0x75u && e <= 0x82u)) c++;
        }
        atomicAdd(&cnt, c);
        __syncthreads();
        if (t == 0) flags[1] = (cnt > 3000) ? 1 : 0;
    }
}

// ---------------- qkv128: mode-0 GEMM, 128x64 tile, 8x4 microtile (split rows) ----
__global__ __launch_bounds__(256) void qkv128_kernel(
    const void* __restrict__ A, const void* __restrict__ W,
    float* __restrict__ oq, float* __restrict__ ok, float* __restrict__ ov,
    const int* __restrict__ flags)
{
    __shared__ __align__(16) float As[16][132];
    __shared__ __align__(16) float Bs[16][64];
    int bf = flags[1];
    const float* A32 = (const float*)A;
    const float* W32 = (const float*)W;
    const unsigned short* A16 = (const unsigned short*)A;
    const unsigned short* W16 = (const unsigned short*)W;
    int m0 = blockIdx.x * 128;
    int n0 = blockIdx.y * 64;
    int id = threadIdx.x;
    int tm = id >> 4, tn = id & 15;
    float acc[8][4] = {};
    for (int k0 = 0; k0 < 256; k0 += 16) {
        int r = id >> 1, ck = (id & 1) * 8;
        int rk = id >> 4, cn = (id & 15) * 4;
        if (bf) {
            uint4 a4 = *(const uint4*)&A16[(size_t)(m0 + r) * 256 + k0 + ck];
            As[ck + 0][r] = b2f(a4.x & 0xFFFFu); As[ck + 1][r] = b2f(a4.x >> 16);
            As[ck + 2][r] = b2f(a4.y & 0xFFFFu); As[ck + 3][r] = b2f(a4.y >> 16);
            As[ck + 4][r] = b2f(a4.z & 0xFFFFu); As[ck + 5][r] = b2f(a4.z >> 16);
            As[ck + 6][r] = b2f(a4.w & 0xFFFFu); As[ck + 7][r] = b2f(a4.w >> 16);
            uint2 w2 = *(const uint2*)&W16[(size_t)(k0 + rk) * 768 + n0 + cn];
            Bs[rk][cn + 0] = b2f(w2.x & 0xFFFFu); Bs[rk][cn + 1] = b2f(w2.x >> 16);
            Bs[rk][cn + 2] = b2f(w2.y & 0xFFFFu); Bs[rk][cn + 3] = b2f(w2.y >> 16);
        } else {
            float4 a0 = *(const float4*)&A32[(size_t)(m0 + r) * 256 + k0 + ck];
            float4 a1 = *(const float4*)&A32[(size_t)(m0 + r) * 256 + k0 + ck + 4];
            As[ck + 0][r] = a0.x; As[ck + 1][r] = a0.y;
            As[ck + 2][r] = a0.z; As[ck + 3][r] = a0.w;
            As[ck + 4][r] = a1.x; As[ck + 5][r] = a1.y;
            As[ck + 6][r] = a1.z; As[ck + 7][r] = a1.w;
            *(float4*)&Bs[rk][cn] = *(const float4*)&W32[(size_t)(k0 + rk) * 768 + n0 + cn];
        }
        __syncthreads();
        #pragma unroll
        for (int kk = 0; kk < 16; kk++) {
            float a[8], b[4];
            *(float4*)&a[0] = *(const float4*)&As[kk][tm * 4];
            *(float4*)&a[4] = *(const float4*)&As[kk][64 + tm * 4];
            *(float4*)&b[0] = *(const float4*)&Bs[kk][tn * 4];
            #pragma unroll
            for (int i = 0; i < 8; i++)
                #pragma unroll
                for (int j = 0; j < 4; j++)
                    acc[i][j] = fmaf(a[i], b[j], acc[i][j]);
        }
        __syncthreads();
    }
    int sec = n0 >> 8;
    int b = m0 >> 12;
    if (sec < 2) {
        int rr0 = (m0 & 4095) + tm * 4;
        float* dstb = (sec == 0) ? oq : ok;
        #pragma unroll
        for (int j = 0; j < 4; j++) {
            int col = n0 + tn * 4 + j;
            int hh = (col >> 5) & 7, d = col & 31;
            size_t base = (((size_t)(b * 8 + hh)) * 32 + d) * 4096 + rr0;
            *(float4*)&dstb[base]      = make_float4(acc[0][j], acc[1][j], acc[2][j], acc[3][j]);
            *(float4*)&dstb[base + 64] = make_float4(acc[4][j], acc[5][j], acc[6][j], acc[7][j]);
        }
    } else {
        int col0 = n0 + tn * 4;
        int hh = (col0 >> 5) & 7, d0 = col0 & 31;
        #pragma unroll
        for (int i = 0; i < 8; i++) {
            int rr = (m0 & 4095) + (i < 4 ? tm * 4 + i : 64 + tm * 4 + (i - 4));
            *(float4*)&ov[(((size_t)(b * 8 + hh)) * 4096 + rr) * 32 + d0] =
                make_float4(acc[i][0], acc[i][1], acc[i][2], acc[i][3]);
        }
    }
}

// ---------------- qkv (mode-1, kernal): 64x64 tile ----------------
__global__ __launch_bounds__(256) void qkv_kernel(
    const void* __restrict__ A, const void* __restrict__ W,
    float* __restrict__ oq, float* __restrict__ ok, float* __restrict__ ov,
    const int* __restrict__ flags)
{
    __shared__ __align__(16) float As[16][68];
    __shared__ __align__(16) float Bs[16][64];
    int bf = flags[1];
    const float* A32 = (const float*)A;
    const float* W32 = (const float*)W;
    const unsigned short* A16 = (const unsigned short*)A;
    const unsigned short* W16 = (const unsigned short*)W;
    int m0 = blockIdx.x * 64;
    int n0 = blockIdx.y * 64;
    int id = threadIdx.x;
    int tm = id >> 4, tn = id & 15;
    float acc[4][4] = {};
    for (int k0 = 0; k0 < 256; k0 += 16) {
        int r = id >> 2, ck = (id & 3) * 4;
        int rk = id >> 4, cn = (id & 15) * 4;
        if (bf) {
            uint2 a2 = *(const uint2*)&A16[(size_t)(m0 + r) * 256 + k0 + ck];
            As[ck + 0][r] = b2f(a2.x & 0xFFFFu); As[ck + 1][r] = b2f(a2.x >> 16);
            As[ck + 2][r] = b2f(a2.y & 0xFFFFu); As[ck + 3][r] = b2f(a2.y >> 16);
            uint2 w2 = *(const uint2*)&W16[(size_t)(k0 + rk) * 768 + n0 + cn];
            Bs[rk][cn + 0] = b2f(w2.x & 0xFFFFu); Bs[rk][cn + 1] = b2f(w2.x >> 16);
            Bs[rk][cn + 2] = b2f(w2.y & 0xFFFFu); Bs[rk][cn + 3] = b2f(w2.y >> 16);
        } else {
            float4 a4 = *(const float4*)&A32[(size_t)(m0 + r) * 256 + k0 + ck];
            As[ck + 0][r] = a4.x; As[ck + 1][r] = a4.y;
            As[ck + 2][r] = a4.z; As[ck + 3][r] = a4.w;
            *(float4*)&Bs[rk][cn] = *(const float4*)&W32[(size_t)(k0 + rk) * 768 + n0 + cn];
        }
        __syncthreads();
        #pragma unroll
        for (int kk = 0; kk < 16; kk++) {
            float4 a = *(const float4*)&As[kk][tm * 4];
            float4 b = *(const float4*)&Bs[kk][tn * 4];
            float av[4] = {a.x, a.y, a.z, a.w};
            float bv[4] = {b.x, b.y, b.z, b.w};
            #pragma unroll
            for (int i = 0; i < 4; i++)
                #pragma unroll
                for (int j = 0; j < 4; j++)
                    acc[i][j] = fmaf(av[i], bv[j], acc[i][j]);
        }
        __syncthreads();
    }
    #pragma unroll
    for (int i = 0; i < 4; i++) {
        int row = m0 + tm * 4 + i;
        int b = row >> 8, rr = row & 255;
        #pragma unroll
        for (int j = 0; j < 4; j++) {
            int col = n0 + tn * 4 + j;
            int s2 = col >> 8, hh = (col >> 5) & 7, d = col & 31;
            float* dst = s2 == 0 ? oq : (s2 == 1 ? ok : ov);
            dst[(((size_t)(b * 8 + hh)) * 256 + rr) * 32 + d] = acc[i][j];
        }
    }
}

// ---------------- mask bit-packing ----------------
__global__ __launch_bounds__(256) void maskpack_kernel(
    const void* __restrict__ mask, unsigned int* __restrict__ maskT,
    const int* __restrict__ flags)
{
    int bh = blockIdx.x >> 7;
    int x0 = (blockIdx.x & 127) * 32;
    int t = threadIdx.x;
    int wv = t >> 6, lane = t & 63;
    int mode = flags[0];
    __shared__ unsigned int lds[32][8];
    for (int it = 0; it < 8; it++) {
        int xl = wv * 8 + it;
        size_t rb = ((size_t)bh * 4096 + x0 + xl) * 256;
        unsigned int nib;
        if (mode == 0) {
            uint4 m = ((const uint4*)((const unsigned int*)mask + rb))[lane];
            nib = (unsigned int)(m.x != 0u) | ((unsigned int)(m.y != 0u) << 1)
                | ((unsigned int)(m.z != 0u) << 2) | ((unsigned int)(m.w != 0u) << 3);
        } else if (mode == 1) {
            unsigned int m = ((const unsigned int*)mask)[rb / 4 + lane];
            nib = (unsigned int)((m & 0xFFu) != 0u) | ((unsigned int)((m & 0xFF00u) != 0u) << 1)
                | ((unsigned int)((m & 0xFF0000u) != 0u) << 2)
                | ((unsigned int)((m & 0xFF000000u) != 0u) << 3);
        } else {
            uint2 m = ((const uint2*)((const unsigned short*)mask + rb))[lane];
            nib = (unsigned int)((m.x & 0xFFFFu) != 0u) | ((unsigned int)((m.x >> 16) != 0u) << 1)
                | ((unsigned int)((m.y & 0xFFFFu) != 0u) << 2)
                | ((unsigned int)((m.y >> 16) != 0u) << 3);
        }
        unsigned long long b0 = __ballot((nib & 1u) != 0u);
        unsigned long long b1 = __ballot((nib & 2u) != 0u);
        unsigned long long b2 = __ballot((nib & 4u) != 0u);
        unsigned long long b3 = __ballot((nib & 8u) != 0u);
        if (lane < 8) {
            int j = lane >> 1;
            unsigned long long bb = j == 0 ? b0 : j == 1 ? b1 : j == 2 ? b2 : b3;
            lds[xl][lane] = (lane & 1) ? (unsigned int)(bb >> 32) : (unsigned int)bb;
        }
    }
    __syncthreads();
    int widx = (t & 3) * 2 + (t >> 7);
    int bitpos = (t >> 2) & 31;
    unsigned int w = 0u;
    #pragma unroll
    for (int xl = 0; xl < 32; xl++)
        w |= ((lds[xl][widx] >> bitpos) & 1u) << xl;
    maskT[((size_t)bh * 256 + t) * 128 + (x0 >> 5)] = w;
}

// ---------------- S1 = scale * kq (256x32) @ xkT (32x4096), FULL batch ----------------
__global__ __launch_bounds__(256) void s1_kernel(
    const float* __restrict__ kq, const float* __restrict__ xkT, float* __restrict__ S)
{
    __shared__ __align__(16) float Aq[32][68];
    __shared__ __align__(16) float Bs[32][64];
    size_t bhg = (size_t)blockIdx.z;
    int k0 = blockIdx.y * 64;
    int x0 = blockIdx.x * 64;
    int id = threadIdx.x;
    {
        int c4 = (id & 7) * 4;
        #pragma unroll
        for (int rep = 0; rep < 2; rep++) {
            int r = (id >> 3) + rep * 32;
            float4 a = *(const float4*)&kq[(bhg * 256 + k0 + r) * 32 + c4];
            Aq[c4 + 0][r] = a.x; Aq[c4 + 1][r] = a.y;
            Aq[c4 + 2][r] = a.z; Aq[c4 + 3][r] = a.w;
        }
    }
    {
        int c = (id & 15) * 4;
        #pragma unroll
        for (int rep = 0; rep < 2; rep++) {
            int r = (id >> 4) + rep * 16;
            *(float4*)&Bs[r][c] = *(const float4*)&xkT[(bhg * 32 + r) * 4096 + x0 + c];
        }
    }
    __syncthreads();
    int tm = id >> 4, tn = id & 15;
    float acc[4][4] = {};
    #pragma unroll
    for (int dd = 0; dd < 32; dd++) {
        float4 a = *(const float4*)&Aq[dd][tm * 4];
        float4 b = *(const float4*)&Bs[dd][tn * 4];
        float av[4] = {a.x, a.y, a.z, a.w};
        float bv[4] = {b.x, b.y, b.z, b.w};
        #pragma unroll
        for (int i = 0; i < 4; i++)
            #pragma unroll
            for (int j = 0; j < 4; j++)
                acc[i][j] = fmaf(av[i], bv[j], acc[i][j]);
    }
    #pragma unroll
    for (int i = 0; i < 4; i++) {
        float4 o;
        o.x = acc[i][0] * SCALE; o.y = acc[i][1] * SCALE;
        o.z = acc[i][2] * SCALE; o.w = acc[i][3] * SCALE;
        *(float4*)&S[(bhg * 256 + k0 + tm * 4 + i) * 4096 + x0 + tn * 4] = o;
    }
}

// ---------------- path-1: argmax + bias + softmax; P stored as bf16 in row's 2nd half ----
__global__ __launch_bounds__(256) void p1_softmax_kernel(
    float* __restrict__ S,
    const int* __restrict__ rd, const int* __restrict__ polar,
    const unsigned int* __restrict__ maskT,
    const void* __restrict__ dis_emb, const void* __restrict__ polar_emb,
    int* __restrict__ mori, const int* __restrict__ flags)
{
    int idx = blockIdx.x;
    int b = idx >> 11;
    int k = (idx >> 3) & 255;
    int h = idx & 7;
    int bh = b * 8 + h;
    int bhk = bh * 256 + k;
    int t = threadIdx.x;
    int bf = flags[1];
    __shared__ float disc[66];
    __shared__ float pem[8];
    __shared__ float osum[8];
    __shared__ float red[8];
    __shared__ int mo_s;
    if (t < 66) disc[t] = bf ? b2f(((const unsigned short*)dis_emb)[t * 8 + h])
                             : ((const float*)dis_emb)[t * 8 + h];
    if (t < 8) {
        pem[t] = bf ? b2f(((const unsigned short*)polar_emb)[t])
                    : ((const float*)polar_emb)[t];
        osum[t] = 0.f;
    }
    __syncthreads();

    float* srow = &S[(size_t)bhk * 4096];
    const int* prow = &polar[((size_t)b * 256 + k) * 4096];
    const int* rrow = &rd[((size_t)b * 256 + k) * 4096];

    float s[16]; int po[16];
    float loc[8] = {0.f, 0.f, 0.f, 0.f, 0.f, 0.f, 0.f, 0.f};
    #pragma unroll
    for (int i = 0; i < 16; i++) {
        int x = t + i * 256;
        s[i] = srow[x];
        int p = prow[x];
        p = p < 0 ? 0 : (p > 7 ? 7 : p);
        po[i] = p;
        float a = fabsf(s[i]);
        #pragma unroll
        for (int o = 0; o < 8; o++) loc[o] += (p == o) ? a : 0.f;
    }
    #pragma unroll
    for (int o = 0; o < 8; o++) {
        float v = loc[o];
        #pragma unroll
        for (int m = 32; m; m >>= 1) v += __shfl_xor(v, m);
        if ((t & 63) == 0) atomicAdd(&osum[o], v);
    }
    __syncthreads();
    if (t == 0) {
        float best = osum[0]; int bi = 0;
        #pragma unroll
        for (int o = 1; o < 8; o++) if (osum[o] > best) { best = osum[o]; bi = o; }
        mo_s = bi;
        mori[bhk] = bi;
    }
    __syncthreads();
    int mo = mo_s;
    const unsigned int* mrow = &maskT[(size_t)bhk * 128];
    float mx = -3.4e38f;
    #pragma unroll
    for (int i = 0; i < 16; i++) {
        int x = t + i * 256;
        float bias = disc[rrow[x]] + pem[(po[i] - mo + 8) & 7];
        unsigned int w = mrow[x >> 5];
        float l = (((w >> (x & 31)) & 1u) ? -1e6f : s[i]) + bias;
        s[i] = l;
        mx = fmaxf(mx, l);
    }
    #pragma unroll
    for (int m = 32; m; m >>= 1) mx = fmaxf(mx, __shfl_xor(mx, m));
    if ((t & 63) == 0) red[t >> 6] = mx;
    __syncthreads();
    mx = fmaxf(fmaxf(red[0], red[1]), fmaxf(red[2], red[3]));
    float sum = 0.f;
    #pragma unroll
    for (int i = 0; i < 16; i++) { s[i] = __expf(s[i] - mx); sum += s[i]; }
    #pragma unroll
    for (int m = 32; m; m >>= 1) sum += __shfl_xor(sum, m);
    if ((t & 63) == 0) red[4 + (t >> 6)] = sum;
    __syncthreads();
    sum = red[4] + red[5] + red[6] + red[7];
    float inv = 1.f / sum;
    // bf16 P into the row's own second half (bytes [8K,16K) of this row) -> no aliasing
    unsigned short* srow16 = (unsigned short*)(srow + 2048);
    #pragma unroll
    for (int i = 0; i < 16; i++) srow16[t + i * 256] = f2b(s[i] * inv);
}

// ---------------- av1: LDS-tiled pure GEMM on bf16 P -> k_att (atomics over 16 xs) ----
// grid: (16 xs, 4 ktiles, 32 bh)
__global__ __launch_bounds__(256) void av1_kernel(
    const float* __restrict__ S, const float* __restrict__ xv, float* __restrict__ k_att)
{
    __shared__ __align__(16) float At[64][68];
    __shared__ __align__(16) float Vt[64][32];
    int bhg = blockIdx.z, b = bhg >> 3, h = bhg & 7;
    int k0 = blockIdx.y * 64;
    int xs = blockIdx.x;
    int id = threadIdx.x;
    int r = id >> 2, p = id & 3;
    float acc[8] = {};
    for (int c8 = 0; c8 < 4; c8++) {
        int xc = xs * 256 + c8 * 64;
        if (c8) __syncthreads();
        {
            int c = (id & 7) * 8;
            #pragma unroll
            for (int rep = 0; rep < 2; rep++) {
                int rr = (id >> 3) + rep * 32;
                const unsigned short* prow =
                    (const unsigned short*)(&S[((size_t)bhg * 256 + k0 + rr) * 4096 + 2048]);
                uint4 pk = *(const uint4*)&prow[xc + c];
                float4 e0 = make_float4(b2f(pk.x & 0xFFFFu), b2f(pk.x >> 16),
                                        b2f(pk.y & 0xFFFFu), b2f(pk.y >> 16));
                float4 e1 = make_float4(b2f(pk.z & 0xFFFFu), b2f(pk.z >> 16),
                                        b2f(pk.w & 0xFFFFu), b2f(pk.w >> 16));
                *(float4*)&At[rr][c]     = e0;
                *(float4*)&At[rr][c + 4] = e1;
            }
        }
        {
            int c = (id & 7) * 4;
            #pragma unroll
            for (int rep = 0; rep < 2; rep++) {
                int rr = (id >> 3) + rep * 32;
                *(float4*)&Vt[rr][c] = *(const float4*)&xv[((size_t)bhg * 4096 + xc + rr) * 32 + c];
            }
        }
        __syncthreads();
        #pragma unroll
        for (int q4 = 0; q4 < 64; q4 += 4) {
            float4 av = *(const float4*)&At[r][q4];
            float aa[4] = {av.x, av.y, av.z, av.w};
            #pragma unroll
            for (int u = 0; u < 4; u++) {
                float4 v0 = *(const float4*)&Vt[q4 + u][p * 8];
                float4 v1 = *(const float4*)&Vt[q4 + u][p * 8 + 4];
                acc[0] = fmaf(aa[u], v0.x, acc[0]);
                acc[1] = fmaf(aa[u], v0.y, acc[1]);
                acc[2] = fmaf(aa[u], v0.z, acc[2]);
                acc[3] = fmaf(aa[u], v0.w, acc[3]);
                acc[4] = fmaf(aa[u], v1.x, acc[4]);
                acc[5] = fmaf(aa[u], v1.y, acc[5]);
                acc[6] = fmaf(aa[u], v1.z, acc[6]);
                acc[7] = fmaf(aa[u], v1.w, acc[7]);
            }
        }
    }
    float* dst = &k_att[((size_t)b * 256 + k0 + r) * 256 + h * 32 + p * 8];
    #pragma unroll
    for (int j = 0; j < 8; j++) atomicAdd(&dst[j], acc[j]);
}

// ---------------- fa2: kc=32 chunks, transposed P tile, FULL batch ----
__global__ __launch_bounds__(256) void fa2_kernel(
    const float* __restrict__ kk, const float* __restrict__ xqT, const float* __restrict__ kv,
    const int* __restrict__ rd, const int* __restrict__ polar,
    const unsigned int* __restrict__ maskT,
    const void* __restrict__ dis_emb, const void* __restrict__ polar_emb,
    const int* __restrict__ mori, const int* __restrict__ flags,
    float* __restrict__ x_att)
{
    __shared__ __align__(16) float Aq[32][34];
    __shared__ __align__(16) float Bs[32][64];
    __shared__ __align__(16) float At2[64][34];
    __shared__ __align__(16) float Vt[32][32];
    __shared__ float disc[66];
    __shared__ float pem[8];
    __shared__ int mo_l[256];
    int bhg = blockIdx.y, b = bhg >> 3, h = bhg & 7;
    int x0 = blockIdx.x * 64;
    int id = threadIdx.x;
    int bf = flags[1];
    if (id < 66) disc[id] = bf ? b2f(((const unsigned short*)dis_emb)[id * 8 + h])
                               : ((const float*)dis_emb)[id * 8 + h];
    if (id < 8) pem[id] = bf ? b2f(((const unsigned short*)polar_emb)[id])
                             : ((const float*)polar_emb)[id];
    mo_l[id] = mori[(size_t)bhg * 256 + id];
    {
        int c = (id & 15) * 4;
        #pragma unroll
        for (int rep = 0; rep < 2; rep++) {
            int r = (id >> 4) + rep * 16;
            *(float4*)&Bs[r][c] = *(const float4*)&xqT[((size_t)bhg * 32 + r) * 4096 + x0 + c];
        }
    }
    int tm = id >> 4, tn = id & 15;
    int xr = id >> 2, p = id & 3;
    float acc8[8] = {};
    float m = -3.0e38f, l = 0.f;
    for (int kc = 0; kc < 256; kc += 32) {
        __syncthreads();
        {
            int r = id >> 3, c4 = (id & 7) * 4;
            float4 a = *(const float4*)&kk[((size_t)bhg * 256 + kc + r) * 32 + c4];
            Aq[c4 + 0][r] = a.x; Aq[c4 + 1][r] = a.y;
            Aq[c4 + 2][r] = a.z; Aq[c4 + 3][r] = a.w;
            *(float4*)&Vt[r][c4] = *(const float4*)&kv[((size_t)bhg * 256 + kc + r) * 32 + c4];
        }
        __syncthreads();
        float acc[2][4] = {};
        #pragma unroll
        for (int dd = 0; dd < 32; dd++) {
            float2 a2 = *(const float2*)&Aq[dd][tm * 2];
            float4 b4 = *(const float4*)&Bs[dd][tn * 4];
            float bv[4] = {b4.x, b4.y, b4.z, b4.w};
            #pragma unroll
            for (int j = 0; j < 4; j++) {
                acc[0][j] = fmaf(a2.x, bv[j], acc[0][j]);
                acc[1][j] = fmaf(a2.y, bv[j], acc[1][j]);
            }
        }
        int xb = x0 + tn * 4;
        #pragma unroll
        for (int i = 0; i < 2; i++) {
            int kl = tm * 2 + i;
            int k = kc + kl;
            int mo = mo_l[k];
            size_t rib = ((size_t)b * 256 + k) * 4096 + xb;
            int4 r4 = *(const int4*)&rd[rib];
            int4 p4 = *(const int4*)&polar[rib];
            unsigned int mw = maskT[((size_t)bhg * 256 + k) * 128 + (xb >> 5)];
            int rv[4] = {r4.x, r4.y, r4.z, r4.w};
            int pv[4] = {p4.x, p4.y, p4.z, p4.w};
            #pragma unroll
            for (int j = 0; j < 4; j++) {
                int pp = pv[j];
                pp = pp < 0 ? 0 : (pp > 7 ? 7 : pp);
                float bias = disc[rv[j]] + pem[(pp - mo + 8) & 7];
                float s = acc[i][j] * SCALE;
                At2[tn * 4 + j][kl] =
                    (((mw >> ((xb + j) & 31)) & 1u) ? -1e9f : s) + bias;
            }
        }
        __syncthreads();
        float mc = -3.0e38f;
        #pragma unroll
        for (int q4 = 0; q4 < 32; q4 += 4) {
            float4 v = *(const float4*)&At2[xr][q4];
            mc = fmaxf(mc, fmaxf(fmaxf(v.x, v.y), fmaxf(v.z, v.w)));
        }
        float mn = fmaxf(m, mc);
        float f = __expf(m - mn);
        m = mn;
        l *= f;
        #pragma unroll
        for (int j = 0; j < 8; j++) acc8[j] *= f;
        #pragma unroll
        for (int q4 = 0; q4 < 32; q4 += 4) {
            float4 lv = *(const float4*)&At2[xr][q4];
            float le[4] = {lv.x, lv.y, lv.z, lv.w};
            #pragma unroll
            for (int u = 0; u < 4; u++) {
                float e = __expf(le[u] - m);
                l += e;
                float4 v0 = *(const float4*)&Vt[q4 + u][p * 8];
                float4 v1 = *(const float4*)&Vt[q4 + u][p * 8 + 4];
                acc8[0] = fmaf(e, v0.x, acc8[0]);
                acc8[1] = fmaf(e, v0.y, acc8[1]);
                acc8[2] = fmaf(e, v0.z, acc8[2]);
                acc8[3] = fmaf(e, v0.w, acc8[3]);
                acc8[4] = fmaf(e, v1.x, acc8[4]);
                acc8[5] = fmaf(e, v1.y, acc8[5]);
                acc8[6] = fmaf(e, v1.z, acc8[6]);
                acc8[7] = fmaf(e, v1.w, acc8[7]);
            }
        }
    }
    float inv = 1.f / l;
    float* dst = &x_att[((size_t)b * 4096 + x0 + xr) * 256 + h * 32 + p * 8];
    *(float4*)&dst[0] = make_float4(acc8[0] * inv, acc8[1] * inv, acc8[2] * inv, acc8[3] * inv);
    *(float4*)&dst[4] = make_float4(acc8[4] * inv, acc8[5] * inv, acc8[6] * inv, acc8[7] * inv);
}

// ---------------- final projection ----------------
__global__ __launch_bounds__(256) void proj_kernel(
    const float* __restrict__ A, const void* __restrict__ W, const void* __restrict__ bias,
    float* __restrict__ out, const int* __restrict__ flags)
{
    __shared__ __align__(16) float As[16][68];
    __shared__ __align__(16) float Bs[16][64];
    int bf = flags[1];
    const float* W32 = (const float*)W;
    const unsigned short* W16 = (const unsigned short*)W;
    int m0 = blockIdx.x * 64, n0 = blockIdx.y * 64;
    int id = threadIdx.x, tm = id >> 4, tn = id & 15;
    float acc[4][4] = {};
    for (int k0 = 0; k0 < 256; k0 += 16) {
        int rr = id >> 2, ck = (id & 3) * 4;
        int rk = id >> 4, cn = (id & 15) * 4;
        {
            float4 a4 = *(const float4*)&A[(size_t)(m0 + rr) * 256 + k0 + ck];
            As[ck + 0][rr] = a4.x; As[ck + 1][rr] = a4.y;
            As[ck + 2][rr] = a4.z; As[ck + 3][rr] = a4.w;
        }
        if (bf) {
            uint2 w2 = *(const uint2*)&W16[(size_t)(k0 + rk) * 256 + n0 + cn];
            Bs[rk][cn + 0] = b2f(w2.x & 0xFFFFu); Bs[rk][cn + 1] = b2f(w2.x >> 16);
            Bs[rk][cn + 2] = b2f(w2.y & 0xFFFFu); Bs[rk][cn + 3] = b2f(w2.y >> 16);
        } else {
            *(float4*)&Bs[rk][cn] = *(const float4*)&W32[(size_t)(k0 + rk) * 256 + n0 + cn];
        }
        __syncthreads();
        #pragma unroll
        for (int kk = 0; kk < 16; kk++) {
            float4 a = *(const float4*)&As[kk][tm * 4];
            float4 b = *(const float4*)&Bs[kk][tn * 4];
            float av[4] = {a.x, a.y, a.z, a.w};
            float bv[4] = {b.x, b.y, b.z, b.w};
            #pragma unroll
            for (int i = 0; i < 4; i++)
                #pragma unroll
                for (int j = 0; j < 4; j++)
                    acc[i][j] = fmaf(av[i], bv[j], acc[i][j]);
        }
        __syncthreads();
    }
    #pragma unroll
    for (int i = 0; i < 4; i++) {
        int col = n0 + tn * 4;
        float b0 = bf ? b2f(((const unsigned short*)bias)[col + 0]) : ((const float*)bias)[col + 0];
        float b1 = bf ? b2f(((const unsigned short*)bias)[col + 1]) : ((const float*)bias)[col + 1];
        float b2v = bf ? b2f(((const unsigned short*)bias)[col + 2]) : ((const float*)bias)[col + 2];
        float b3 = bf ? b2f(((const unsigned short*)bias)[col + 3]) : ((const float*)bias)[col + 3];
        float4 o = make_float4(acc[i][0] + b0, acc[i][1] + b1, acc[i][2] + b2v, acc[i][3] + b3);
        *(float4*)&out[(size_t)(m0 + tm * 4 + i) * 256 + col] = o;
    }
}

extern "C" void kernel_launch(void* const* d_in, const int* in_sizes, int n_in,
                              void* d_out, int out_size, void* d_ws, size_t ws_size,
                              hipStream_t stream) {
    (void)in_sizes; (void)n_in; (void)out_size; (void)ws_size;
    const void* x         = d_in[0];
    const void* kern      = d_in[1];
    const int*  rd        = (const int*)d_in[2];
    const int*  polar     = (const int*)d_in[3];
    const void* amask     = d_in[4];
    const void* w_qkv     = d_in[5];
    const void* w_proj    = d_in[6];
    const void* b_proj    = d_in[7];
    const void* polar_emb = d_in[8];
    const void* dis_emb   = d_in[9];
    float* out = (float*)d_out;

    float* ws = (float*)d_ws;
    float* S     = ws + OFF_S;
    float* xqT   = ws + OFF_XQT;
    float* xv    = ws + OFF_XV;
    float* xkT   = ws + OFF_XKT;
    float* kq    = ws + OFF_KQ;
    float* kkM   = ws + OFF_KK;
    float* kvM   = ws + OFF_KV;
    float* k_att = ws + OFF_KATT;
    float* x_att = ws + OFF_XATT;
    unsigned int* maskT = (unsigned int*)(ws + OFF_MT);
    int* mori  = (int*)(ws + OFF_MORI);
    int* flags = (int*)(ws + OFF_FLAG);

    detect_kernel<<<2, 256, 0, stream>>>((const unsigned int*)amask, (const unsigned int*)x, flags);
    qkv128_kernel<<<dim3(128, 12), 256, 0, stream>>>(x, w_qkv, xqT, xkT, xv, flags);
    qkv_kernel<<<dim3(16, 12), 256, 0, stream>>>(kern, w_qkv, kq, kkM, kvM, flags);
    maskpack_kernel<<<4096, 256, 0, stream>>>(amask, maskT, flags);
    hipMemsetAsync(k_att, 0, 262144 * sizeof(float), stream);

    // FULL-batch pipeline
    s1_kernel<<<dim3(64, 4, 32), 256, 0, stream>>>(kq, xkT, S);
    p1_softmax_kernel<<<8192, 256, 0, stream>>>(S, rd, polar, maskT, dis_emb, polar_emb,
                                                mori, flags);
    av1_kernel<<<dim3(16, 4, 32), 256, 0, stream>>>(S, xv, k_att);
    fa2_kernel<<<dim3(64, 32), 256, 0, stream>>>(kkM, xqT, kvM, rd, polar, maskT,
                                                 dis_emb, polar_emb, mori, flags, x_att);

    proj_kernel<<<dim3(256, 4), 256, 0, stream>>>(x_att, w_proj, b_proj, out, flags);
    proj_kernel<<<dim3(16, 4), 256, 0, stream>>>(k_att, w_proj, b_proj, out + 4194304, flags);
}